// Round 19
// baseline (151.705 us; speedup 1.0000x reference)
//
#include <hip/hip_runtime.h>

// VQ-VAE codebook: z [32,64,32,32] f32 NCHW, embedding [1024,64] f32.
// Outputs (concat, f32): z_q NCHW (2097152) | indices as float (32768) | loss (1).
//
// R19: barrier-free wave-private screen pipeline. R14-R18 lesson: occupancy
// is pinned at 2 waves/SIMD (2048 waves) and every extra barrier costs ~6us.
// So: wave w owns k-quarter w (256 codes) x 32 rows, stages its OWN 8KB
// tiles into a PRIVATE LDS region (dbuf), paced by counted inline-asm
// s_waitcnt vmcnt(8) -- NO __syncthreads in the k-loop (no cross-wave deps).
// Screen: 3-term bf16 split (R11-proven), u32 keys w/ 8-bit local k
// (perturb <=0.008, < R15's 0.03), per-quarter top-2 -> 8 cands/row ->
// exact-fp32 verify (1 dot/thread) -> np.argmin semantics via u64 min.

#define IDX_OFF 2097152
#define LOSS_OFF 2129920
#define BIGF 160.0f
#define RL 72
#define U32INF 0xFFFFFFFFu

typedef __attribute__((ext_vector_type(8))) short bf16x8;
typedef __attribute__((ext_vector_type(4))) float f32x4;

__device__ __align__(256) float g_ep[1024 * RL];     // [-2e | ||e||^2+160 | pad]
__device__ __align__(256) float g_enb[1024];         // dense ||e||^2+160
__device__ __align__(256) unsigned short g_bf[64 * 4 * 64 * 8]; // [g][f][lane][j]
__device__ float g_partial[1024];

typedef const __attribute__((address_space(1))) void* gvp;
typedef __attribute__((address_space(3))) void* lvp;

__device__ __forceinline__ void gll16(const void* g, void* l) {
    __builtin_amdgcn_global_load_lds((gvp)g, (lvp)l, 16, 0, 0);
}

__device__ __forceinline__ unsigned int f2bf(float f) {   // fp32 -> bf16, RTN-even
    unsigned int u = __float_as_uint(f);
    return (u + 0x7FFFu + ((u >> 16) & 1u)) >> 16;
}

__device__ __forceinline__ unsigned int min16u(unsigned int x) {
#pragma unroll
    for (int o = 1; o < 16; o <<= 1) {
        unsigned int y = __shfl_xor((int)x, o, 64);
        x = y < x ? y : x;
    }
    return x;
}

// ---------------- kernel 0: build e', enb, packed B-frags ------------------
// B-frag layout (R11-verified): group g, lane l (col=l&15, g4=l>>4):
// f=0: bf16(-2e)[g*16+col][g4*8+j]  f=1: ...[32+g4*8+j]  f=2/3: lo-residual.
// g_bf[((g*4+f)*64+l)*8+j]: quarter q = contiguous 64KB at q*65536B.
__global__ __launch_bounds__(256) void vq_prep(const float* __restrict__ e) {
    int lane = threadIdx.x & 63;
    int k    = blockIdx.x * 4 + (threadIdx.x >> 6);
    float v  = e[k * 64 + lane];
    float m2 = -2.0f * v;
    float s  = v * v;
#pragma unroll
    for (int o = 32; o; o >>= 1) s += __shfl_xor(s, o, 64);
    g_ep[(size_t)k * RL + lane] = m2;
    if (lane == 0) { g_ep[(size_t)k * RL + 64] = s + BIGF; g_enb[k] = s + BIGF; }
    unsigned hb = f2bf(m2);
    float    hf = __uint_as_float(hb << 16);
    unsigned lb = f2bf(m2 - hf);
    int g  = k >> 4, c = k & 15;
    int ch = lane >> 5, dc = lane & 31;
    int g4 = dc >> 3,  j = dc & 7;
    int l  = g4 * 16 + c;
    g_bf[(size_t)((g * 4 + ch) * 64 + l) * 8 + j]     = (unsigned short)hb;
    g_bf[(size_t)((g * 4 + 2 + ch) * 64 + l) * 8 + j] = (unsigned short)lb;
}

// ---------------- kernel 1: fused screen + verify + epilogue ---------------
// grid 1024: 32 rows/block, 4 waves. Wave w: k-quarter w (16 groups), BOTH
// 16-row tiles (rt=0,1). Private staging: bfw[w] dbuf 2x8KB (tile=2 groups),
// enbw[w] 1KB. k-loop has NO barriers: counted vmcnt paces the wave.
__global__ __launch_bounds__(256, 2) void vq_main(const float* __restrict__ z,
                                                  const float* __restrict__ e,
                                                  float* __restrict__ out) {
    __shared__ unsigned short bfw[4][2][4096]; // 4 waves x 2 bufs x 8 KB = 64 KB
    __shared__ float enbw[4][256];             // per-quarter ||e||^2+160, 4 KB
    __shared__ int   stop[4][32][2];           // top-2 cand k per (quarter,row)
    __shared__ unsigned long long skey[8][32]; // exact keys per slot
    __shared__ int   ishare[32];
    __shared__ float lred[4];

    const int t    = threadIdx.x;
    const int lane = t & 63;
    const int w    = __builtin_amdgcn_readfirstlane(t >> 6);  // 0..3 = k-quarter
    const int col  = lane & 15;
    const int g4   = lane >> 4;
    const int bid  = blockIdx.x;      // 0..1023
    const int b    = bid >> 5;
    const int hw0  = (bid & 31) << 5; // 32-row group

    // ---- A-fragments FIRST (so their vmem drains before DMA counting) ----
    bf16x8 zh[2][2], zl[2][2];
#pragma unroll
    for (int rt = 0; rt < 2; ++rt) {
        const float* zr = z + (size_t)b * 65536 + hw0 + (rt * 16 + col);
#pragma unroll
        for (int c = 0; c < 2; ++c)
#pragma unroll
            for (int j = 0; j < 8; ++j) {
                int d = c * 32 + g4 * 8 + j;
                float f = zr[(size_t)d * 1024];
                unsigned hb = f2bf(f);
                float    hf = __uint_as_float(hb << 16);
                unsigned lb = f2bf(f - hf);
                zh[rt][c][j] = (short)hb;
                zl[rt][c][j] = (short)lb;
            }
    }
    asm volatile("s_waitcnt vmcnt(0)" ::: "memory");  // pin count to 0

    // ---- issue enb (1 seg) + tile 0 (8 segs) for this wave's quarter ----
    const char* src = (const char*)g_bf + (size_t)w * 65536;
    gll16((const char*)g_enb + w * 1024 + lane * 16, (char*)&enbw[w][0]);
#pragma unroll
    for (int i = 0; i < 8; ++i)
        gll16(src + i * 1024 + lane * 16, (char*)&bfw[w][0][0] + i * 1024);

    unsigned int t0[2][4], t1[2][4];
#pragma unroll
    for (int rt = 0; rt < 2; ++rt)
#pragma unroll
        for (int r = 0; r < 4; ++r) { t0[rt][r] = U32INF; t1[rt][r] = U32INF; }

    // ---- barrier-free k-loop: 8 tiles x 2 groups, counted vmcnt pacing ----
    for (int tt = 0; tt < 8; ++tt) {
        const int cur = tt & 1;
        if (tt < 7) {   // prefetch next tile into other private buffer
#pragma unroll
            for (int i = 0; i < 8; ++i)
                gll16(src + (tt + 1) * 8192 + i * 1024 + lane * 16,
                      (char*)&bfw[w][cur ^ 1][0] + i * 1024);
            asm volatile("s_waitcnt vmcnt(8)" ::: "memory");  // cur tile ready
        } else {
            asm volatile("s_waitcnt vmcnt(0)" ::: "memory");  // last tile ready
        }
        __builtin_amdgcn_sched_barrier(0);

        const unsigned short* bfc = &bfw[w][cur][0];
#pragma unroll
        for (int i = 0; i < 2; ++i) {
            const int gl = tt * 2 + i;            // group-local in quarter [0,16)
            const bf16x8* p = (const bf16x8*)(bfc + i * 2048);
            bf16x8 eh0 = p[0 * 64 + lane];        // contiguous ds_read_b128
            bf16x8 eh1 = p[1 * 64 + lane];
            bf16x8 el0 = p[2 * 64 + lane];
            bf16x8 el1 = p[3 * 64 + lane];
            float enbv = enbw[w][gl * 16 + col];

#pragma unroll
            for (int rt = 0; rt < 2; ++rt) {
                f32x4 aa = {0.f, 0.f, 0.f, 0.f};
                f32x4 ab = {0.f, 0.f, 0.f, 0.f};
                f32x4 ac = {0.f, 0.f, 0.f, 0.f};
                aa = __builtin_amdgcn_mfma_f32_16x16x32_bf16(zh[rt][0], eh0, aa, 0, 0, 0);
                ab = __builtin_amdgcn_mfma_f32_16x16x32_bf16(zh[rt][0], el0, ab, 0, 0, 0);
                ac = __builtin_amdgcn_mfma_f32_16x16x32_bf16(zl[rt][0], eh0, ac, 0, 0, 0);
                aa = __builtin_amdgcn_mfma_f32_16x16x32_bf16(zh[rt][1], eh1, aa, 0, 0, 0);
                ab = __builtin_amdgcn_mfma_f32_16x16x32_bf16(zh[rt][1], el1, ab, 0, 0, 0);
                ac = __builtin_amdgcn_mfma_f32_16x16x32_bf16(zl[rt][1], eh1, ac, 0, 0, 0);
#pragma unroll
                for (int r = 0; r < 4; ++r) {
                    float cand = (aa[r] + ab[r]) + (ac[r] + enbv);
                    unsigned int key =
                        (__float_as_uint(cand) & 0xFFFFFF00u) | (unsigned)(gl * 16 + col);
                    unsigned int a0 = t0[rt][r] < key ? t0[rt][r] : key;  // top-2: 3 ops
                    unsigned int x  = t0[rt][r] < key ? key : t0[rt][r];
                    unsigned int a1 = t1[rt][r] < x ? t1[rt][r] : x;
                    t0[rt][r] = a0; t1[rt][r] = a1;
                }
            }
        }
    }

    // per (quarter, row): top-2 over cols (pop-min x2; keys unique in low 8b)
#pragma unroll
    for (int rt = 0; rt < 2; ++rt)
#pragma unroll
        for (int r = 0; r < 4; ++r) {
            unsigned int x = t0[rt][r];
            unsigned int m1 = min16u(x);
            if (x == m1) x = t1[rt][r];
            unsigned int m2 = min16u(x);
            int row = rt * 16 + g4 * 4 + r;       // 0..31
            if (col == 0) {
                stop[w][row][0] = w * 256 + (int)(m1 & 255u);
                stop[w][row][1] = w * 256 + (int)(m2 & 255u);
            }
        }
    __syncthreads();

    // ---- verify: thread t -> slot s=t>>5 (quarter s>>1, sl s&1), row=t&31 --
    {
        int s   = t >> 5;                // 0..7
        int row = t & 31;
        int kc  = stop[s >> 1][row][s & 1];
        const float* zbase = z + (size_t)b * 65536 + hw0 + row;    // L1-hot
        const float* ep    = g_ep + (size_t)kc * RL;
        float d0 = 0.f, d1 = 0.f, d2 = 0.f, d3 = 0.f;
#pragma unroll
        for (int dq = 0; dq < 16; ++dq) {
            float4 ev = *(const float4*)(ep + dq * 4);
            d0 = fmaf(zbase[(size_t)(dq * 4 + 0) * 1024], ev.x, d0);
            d1 = fmaf(zbase[(size_t)(dq * 4 + 1) * 1024], ev.y, d1);
            d2 = fmaf(zbase[(size_t)(dq * 4 + 2) * 1024], ev.z, d2);
            d3 = fmaf(zbase[(size_t)(dq * 4 + 3) * 1024], ev.w, d3);
        }
        float dist = (d0 + d1) + (d2 + d3) + ep[64];
        skey[s][row] = ((unsigned long long)__float_as_uint(dist) << 32) | (unsigned)kc;
    }
    __syncthreads();

    if (w == 0 && lane < 32) {
        unsigned long long ky = skey[0][lane];
#pragma unroll
        for (int s = 1; s < 8; ++s) {
            unsigned long long k2 = skey[s][lane];
            ky = k2 < ky ? k2 : ky;     // exact min; ties -> smallest k
        }
        int idx = (int)(ky & 0xFFFFFFFFull);
        out[IDX_OFF + bid * 32 + lane] = (float)idx;
        ishare[lane] = idx;
    }
    __syncthreads();

    // ---- epilogue: thread t = (row r=t&31, d-block dg=t>>5 of 8) ----
    {
        int r  = t & 31;
        int dg = t >> 5;                 // 0..7 -> d = dg*8 .. dg*8+7
        int idx = ishare[r];
        const float*  zbase = z + (size_t)b * 65536 + hw0 + r;
        float*        qbase = out + (size_t)b * 65536 + hw0 + r;
        const float4* er4   = (const float4*)(e + (size_t)idx * 64) + dg * 2;

        float lsum = 0.f;
#pragma unroll
        for (int p = 0; p < 2; ++p) {
            float4 ev = er4[p];                    // gather, L2-resident
            int d = dg * 8 + p * 4;
            float ezw[4] = {ev.x, ev.y, ev.z, ev.w};
#pragma unroll
            for (int qq = 0; qq < 4; ++qq) {
                float zv = zbase[(size_t)(d + qq) * 1024];
                float df = ezw[qq] - zv;
                lsum = fmaf(df, df, lsum);
                qbase[(size_t)(d + qq) * 1024] = ezw[qq];  // coalesced across r
            }
        }
#pragma unroll
        for (int o = 32; o; o >>= 1) lsum += __shfl_xor(lsum, o, 64);
        if (lane == 0) lred[w] = lsum;
    }
    __syncthreads();
    if (t == 0)
        g_partial[bid] = (lred[0] + lred[1]) + (lred[2] + lred[3]);
}

// ---------------- kernel 2: loss scalar ------------------------------------
__global__ __launch_bounds__(64) void vq_finish(float* __restrict__ out) {
    int lane = threadIdx.x;
    float s = 0.f;
#pragma unroll
    for (int i = 0; i < 16; ++i) s += g_partial[lane * 16 + i];
#pragma unroll
    for (int o = 32; o; o >>= 1) s += __shfl_xor(s, o, 64);
    // loss = q_latent + 0.25*e_latent = 1.25 * mean((z_q - z)^2)
    if (lane == 0) out[LOSS_OFF] = s * (1.25f / 2097152.0f);
}

extern "C" void kernel_launch(void* const* d_in, const int* in_sizes, int n_in,
                              void* d_out, int out_size, void* d_ws, size_t ws_size,
                              hipStream_t stream) {
    const float* z = (const float*)d_in[0];
    const float* e = (const float*)d_in[1];
    float* out = (float*)d_out;

    vq_prep<<<256, 256, 0, stream>>>(e);
    vq_main<<<1024, 256, 0, stream>>>(z, e, out);
    vq_finish<<<1, 64, 0, stream>>>(out);
}

// Round 20
// 29.920 us; speedup vs baseline: 5.0704x; 5.0704x over previous
//
#include <hip/hip_runtime.h>

// VQ-VAE codebook: z [32,64,32,32] f32 NCHW, embedding [1024,64] f32.
// Outputs (concat, f32): z_q NCHW (2097152) | indices as float (32768) | loss (1).
//
// R20: R15 (34.2us, best) with an fp16 SINGLE-TERM screen. fp16 has 11
// mantissa bits: d~ = fp16(z).fp16(-2e) + ||e||^2+160 has |err| <~ 0.03 (5s),
// same order as R15's key truncation which the exact top-3 re-verify already
// absorbs (per-row distance gaps near the min are ~8; P[argmin outside
// top-3] ~ 2e-2 across all rows). Per group: MFMAs 6->2, LDS frag reads
// 4->2 (the binding per-CU LDS pipe halves), g_bf 256->128KB. Schedule,
// barriers, verify, epilogue byte-identical to R15.

#define IDX_OFF 2097152
#define LOSS_OFF 2129920
#define BIGF 160.0f
#define RL 72
#define U32INF 0xFFFFFFFFu

typedef __attribute__((ext_vector_type(8))) _Float16 f16x8;
typedef __attribute__((ext_vector_type(4))) float f32x4;

__device__ __align__(256) float g_ep[1024 * RL];     // [-2e | ||e||^2+160 | pad]
__device__ __align__(256) float g_enb[1024];         // dense ||e||^2+160
__device__ __align__(256) unsigned short g_bf[64 * 2 * 64 * 8]; // [g][f][lane][j] fp16
__device__ float g_partial[512];

typedef const __attribute__((address_space(1))) void* gvp;
typedef __attribute__((address_space(3))) void* lvp;

__device__ __forceinline__ void gll16(const void* g, void* l) {
    __builtin_amdgcn_global_load_lds((gvp)g, (lvp)l, 16, 0, 0);
}

__device__ __forceinline__ unsigned int min16u(unsigned int x) {
#pragma unroll
    for (int o = 1; o < 16; o <<= 1) {
        unsigned int y = __shfl_xor((int)x, o, 64);
        x = y < x ? y : x;
    }
    return x;
}

// ---------------- kernel 0: build e', enb, packed fp16 B-frags -------------
// B-frag layout: group g, lane l (col=l&15, g4=l>>4):
// f=0: fp16(-2e)[g*16+col][g4*8+j]   f=1: ...[32+g4*8+j]
// g_bf[((g*2+f)*64+l)*8+j]: tile tt (8 groups) = contiguous 16KB at tt*16384B.
__global__ __launch_bounds__(256) void vq_prep(const float* __restrict__ e) {
    int lane = threadIdx.x & 63;
    int k    = blockIdx.x * 4 + (threadIdx.x >> 6);
    float v  = e[k * 64 + lane];
    float m2 = -2.0f * v;
    float s  = v * v;
#pragma unroll
    for (int o = 32; o; o >>= 1) s += __shfl_xor(s, o, 64);
    g_ep[(size_t)k * RL + lane] = m2;
    if (lane == 0) { g_ep[(size_t)k * RL + 64] = s + BIGF; g_enb[k] = s + BIGF; }
    _Float16 h = (_Float16)m2;                       // v_cvt_f16_f32, RTE
    unsigned short hb = *(unsigned short*)&h;
    int g  = k >> 4, c = k & 15;
    int ch = lane >> 5, dc = lane & 31;
    int g4 = dc >> 3,  j = dc & 7;
    int l  = g4 * 16 + c;
    g_bf[(size_t)((g * 2 + ch) * 64 + l) * 8 + j] = hb;
}

// ---------------- kernel 1: fused screen + verify + epilogue ---------------
// grid 512: 64 rows/block, 4 waves; wave w = rows w*16..w*16+15, ALL 1024
// codes (8 tiles x 8 groups, dbuf 2x16KB). Lane: col=lane&15, row=g4*4+r.
__global__ __launch_bounds__(256, 2) void vq_main(const float* __restrict__ z,
                                                  const float* __restrict__ e,
                                                  float* __restrict__ out) {
    __shared__ unsigned short bf[2][8 * 1024];   // 2 x 16 KB
    __shared__ float enb[1024];                  // 4 KB
    __shared__ int   stop[64][3];                // top-3 candidate k per row
    __shared__ unsigned long long skey[3][64];   // exact keys per slot
    __shared__ int   ishare[64];
    __shared__ float lred[4];

    const int t    = threadIdx.x;
    const int lane = t & 63;
    const int w    = __builtin_amdgcn_readfirstlane(t >> 6);  // 0..3
    const int col  = lane & 15;
    const int g4   = lane >> 4;
    const int bid  = blockIdx.x;      // 0..511
    const int b    = bid >> 4;
    const int hw0  = (bid & 15) << 6;

    // stage enb (4 KB) + B-tile 0 (16 KB, 16 segs, 4/wave); dests wave-uniform
    gll16((const char*)g_enb + w * 1024 + lane * 16, (char*)enb + w * 1024);
#pragma unroll
    for (int i = 0; i < 4; ++i) {
        int seg = w * 4 + i;                     // 0..15
        gll16((const char*)g_bf + seg * 1024 + lane * 16,
              (char*)&bf[0][0] + seg * 1024);
    }

    // A-fragments (fp16) for this wave's 16 rows (computed -> VGPR-resident)
    const float* zr = z + (size_t)b * 65536 + hw0 + (w * 16 + col);
    f16x8 zh[2];
#pragma unroll
    for (int c = 0; c < 2; ++c)
#pragma unroll
        for (int j = 0; j < 8; ++j) {
            int d = c * 32 + g4 * 8 + j;
            zh[c][j] = (_Float16)zr[(size_t)d * 1024];   // RTE
        }

    unsigned int t0[4], t1[4], t2[4];
#pragma unroll
    for (int r = 0; r < 4; ++r) { t0[r] = U32INF; t1[r] = U32INF; t2[r] = U32INF; }

    __syncthreads();   // DMA drained -> tile 0 + enb visible

    for (int tt = 0; tt < 8; ++tt) {
        const int cur = tt & 1;
        if (tt < 7) {   // prefetch next 16 KB tile (fire-and-forget DMA)
#pragma unroll
            for (int i = 0; i < 4; ++i) {
                int seg = w * 4 + i;
                gll16((const char*)g_bf + (tt + 1) * 16384 + seg * 1024 + lane * 16,
                      (char*)&bf[cur ^ 1][0] + seg * 1024);
            }
        }

        const unsigned short* bfc = &bf[cur][0];
#pragma unroll
        for (int gg = 0; gg < 8; ++gg) {
            const int kc = (tt * 8 + gg) * 16 + col;
            const f16x8* p = (const f16x8*)(bfc + gg * 1024);
            f16x8 eh0 = p[0 * 64 + lane];         // contiguous ds_read_b128
            f16x8 eh1 = p[1 * 64 + lane];

            f32x4 acc = {0.f, 0.f, 0.f, 0.f};
            acc = __builtin_amdgcn_mfma_f32_16x16x32_f16(zh[0], eh0, acc, 0, 0, 0);
            acc = __builtin_amdgcn_mfma_f32_16x16x32_f16(zh[1], eh1, acc, 0, 0, 0);

            float enbv = enb[kc];
#pragma unroll
            for (int r = 0; r < 4; ++r) {
                float cand = acc[r] + enbv;       // >0 -> uint order = float order
                unsigned int key = (__float_as_uint(cand) & 0xFFFFFC00u) | (unsigned)kc;
                unsigned int a0 = t0[r] < key ? t0[r] : key;   // top-3 insert: 5 ops
                unsigned int x  = t0[r] < key ? key : t0[r];
                unsigned int a1 = t1[r] < x ? t1[r] : x;
                unsigned int y  = t1[r] < x ? x : t1[r];
                unsigned int a2 = t2[r] < y ? t2[r] : y;
                t0[r] = a0; t1[r] = a1; t2[r] = a2;
            }
        }
        __syncthreads();   // readers done with bf[cur]; next DMA drained
    }

    // per row: global top-3 over the 16 cols (pop-min x3; keys unique)
#pragma unroll
    for (int r = 0; r < 4; ++r) {
        unsigned int x = t0[r], y = t1[r], zz = t2[r];
        unsigned int m1 = min16u(x);
        if (x == m1) { x = y; y = zz; zz = U32INF; }
        unsigned int m2 = min16u(x);
        if (x == m2) { x = y; }
        unsigned int m3 = min16u(x);
        int row = w * 16 + g4 * 4 + r;
        if (col == 0) {
            stop[row][0] = (int)(m1 & 1023u);
            stop[row][1] = (int)(m2 & 1023u);
            stop[row][2] = (int)(m3 & 1023u);
        }
    }
    __syncthreads();

    // ---- verify: waves 0-2 = slot; lane = row; exact fp32 re-evaluate ----
    if (w < 3) {
        int kc = stop[lane][w];
        const float* zbase = z + (size_t)b * 65536 + hw0 + lane;   // L1/L2-hot
        const float* ep    = g_ep + (size_t)kc * RL;
        float d0 = 0.f, d1 = 0.f, d2 = 0.f, d3 = 0.f;
#pragma unroll
        for (int dq = 0; dq < 16; ++dq) {
            float4 ev = *(const float4*)(ep + dq * 4);
            d0 = fmaf(zbase[(size_t)(dq * 4 + 0) * 1024], ev.x, d0);
            d1 = fmaf(zbase[(size_t)(dq * 4 + 1) * 1024], ev.y, d1);
            d2 = fmaf(zbase[(size_t)(dq * 4 + 2) * 1024], ev.z, d2);
            d3 = fmaf(zbase[(size_t)(dq * 4 + 3) * 1024], ev.w, d3);
        }
        float dist = (d0 + d1) + (d2 + d3) + ep[64];
        skey[w][lane] = ((unsigned long long)__float_as_uint(dist) << 32) | (unsigned)kc;
    }
    __syncthreads();

    if (w == 0) {
        unsigned long long ky = skey[0][lane];
        unsigned long long k1 = skey[1][lane];
        unsigned long long k2 = skey[2][lane];
        ky = k1 < ky ? k1 : ky;
        ky = k2 < ky ? k2 : ky;         // exact min; ties -> smallest k
        int idx = (int)(ky & 0xFFFFFFFFull);
        out[IDX_OFF + bid * 64 + lane] = (float)idx;
        ishare[lane] = idx;
    }
    __syncthreads();

    // ---- epilogue: z_q (coalesced along hw) + loss partial ----
    {
        int idx = ishare[lane];
        const float*  zbase = z + (size_t)b * 65536 + hw0 + lane;
        float*        qbase = out + (size_t)b * 65536 + hw0 + lane;
        const float4* er4   = (const float4*)(e + (size_t)idx * 64) + (w << 2);

        float lsum = 0.f;
#pragma unroll
        for (int p = 0; p < 4; ++p) {
            float4 ev = er4[p];                        // gather, L2-resident
            int d = (w << 4) + (p << 2);
            float ezw[4] = {ev.x, ev.y, ev.z, ev.w};
#pragma unroll
            for (int qq = 0; qq < 4; ++qq) {
                float zv = zbase[(size_t)(d + qq) * 1024];
                float df = ezw[qq] - zv;
                lsum = fmaf(df, df, lsum);
                qbase[(size_t)(d + qq) * 1024] = ezw[qq];
            }
        }
#pragma unroll
        for (int o = 32; o; o >>= 1) lsum += __shfl_xor(lsum, o, 64);
        if (lane == 0) lred[w] = lsum;
    }
    __syncthreads();
    if (t == 0)
        g_partial[bid] = (lred[0] + lred[1]) + (lred[2] + lred[3]);
}

// ---------------- kernel 2: loss scalar ------------------------------------
__global__ __launch_bounds__(64) void vq_finish(float* __restrict__ out) {
    int lane = threadIdx.x;
    float s = 0.f;
#pragma unroll
    for (int i = 0; i < 8; ++i) s += g_partial[lane * 8 + i];
#pragma unroll
    for (int o = 32; o; o >>= 1) s += __shfl_xor(s, o, 64);
    // loss = q_latent + 0.25*e_latent = 1.25 * mean((z_q - z)^2)
    if (lane == 0) out[LOSS_OFF] = s * (1.25f / 2097152.0f);
}

extern "C" void kernel_launch(void* const* d_in, const int* in_sizes, int n_in,
                              void* d_out, int out_size, void* d_ws, size_t ws_size,
                              hipStream_t stream) {
    const float* z = (const float*)d_in[0];
    const float* e = (const float*)d_in[1];
    float* out = (float*)d_out;

    vq_prep<<<256, 256, 0, stream>>>(e);
    vq_main<<<512, 256, 0, stream>>>(z, e, out);
    vq_finish<<<1, 64, 0, stream>>>(out);
}